// Round 2
// baseline (1115.105 us; speedup 1.0000x reference)
//
#include <hip/hip_runtime.h>

namespace {
constexpr int CC = 3, FF = 51;
constexpr int HOUT = 384, WOUT = 384;
constexpr int HIN = 434, WIN = 434;
constexpr int KY = 2;                // vertical outputs per thread
constexpr int TX = 64;               // one wave per block
constexpr int EXT = TX - 1 + FF;     // 114 staged f16 elems per channel row
constexpr int LPAD = 120;            // LDS row pitch (f16), 8B-aligned rows
constexpr int NPAIR = 28;            // f16 pairs per horizontal dot
constexpr int NQ = NPAIR / 2;        // 8-byte LDS reads per dot (14)
constexpr int NSTEP = FF + KY - 1;   // 52 input rows per tile (even)
constexpr int NSG = (CC * EXT + TX - 1) / TX;  // staging loads/thread (6)

using half2v = _Float16 __attribute__((ext_vector_type(2)));

__device__ __forceinline__ float fdot2f(half2v a, half2v b, float c) {
#if __has_builtin(__builtin_amdgcn_fdot2)
  return __builtin_amdgcn_fdot2(a, b, c, false);
#else
  return c + (float)a.x * (float)b.x + (float)a.y * (float)b.y;
#endif
}

__device__ __forceinline__ half2v pack_rte(float lo, float hi) {
  half2v r;
  r.x = (_Float16)lo;   // v_cvt_f16_f32 (RTE) — unbiased, unlike cvt_pkrtz
  r.y = (_Float16)hi;
  return r;
}
}  // namespace

__global__ __launch_bounds__(TX, 4) void sepconv_kernel(
    const float* __restrict__ In, const float* __restrict__ Ver,
    const float* __restrict__ Hor, float* __restrict__ Out) {
  const int tid = threadIdx.x;
  const int x0 = blockIdx.x * TX;
  const int y0 = blockIdx.y * KY;
  const int b = blockIdx.z;
  const int x = x0 + tid;
  const int a = tid & 3;      // alignment class (f16 elems)
  const int base4 = tid - a;  // 8B-aligned local window base

  // wave-private double-buffered input strip; NO __syncthreads anywhere
  __shared__ __align__(16) unsigned short sIn[2][CC][LPAD];

  const size_t HW = (size_t)HOUT * WOUT;

  // ---- pack per-pixel horizontal taps: hp[t][j] = (h[2j-a], h[2j-a+1]), OOB->0
  half2v hp[KY][NPAIR];
  {
    const float* horx = Hor + (size_t)b * FF * HW + x;
#pragma unroll
    for (int t = 0; t < KY; ++t) {
      const float* hb = horx + (size_t)(y0 + t) * WOUT;
#pragma unroll
      for (int j = 0; j < NPAIR; ++j) {
        const int lo = 2 * j - a;
        const int hi = lo + 1;
        float flo = (lo >= 0 && lo < FF)
                        ? __builtin_nontemporal_load(&hb[(size_t)lo * HW])
                        : 0.0f;
        float fhi = (hi >= 0 && hi < FF)
                        ? __builtin_nontemporal_load(&hb[(size_t)hi * HW])
                        : 0.0f;
        hp[t][j] = pack_rte(flo, fhi);
      }
    }
  }

  const float* inb = In + (size_t)b * CC * HIN * WIN + x0;
  const float* verb = Ver + (size_t)b * FF * HW + (size_t)y0 * WOUT + x;

  float acc[CC][KY] = {};

  // NOTE: x0 + EXT - 1 = 320 + 113 = 433 < WIN=434 -> no x guard needed.
  auto stage_load = [&](int r, float sv[NSG]) {
#pragma unroll
    for (int k = 0; k < NSG; ++k) {
      const int idx = tid + k * TX;
      sv[k] = 0.0f;
      if (idx < CC * EXT) {
        const int c = idx / EXT;
        const int e = idx - c * EXT;
        sv[k] = inb[(size_t)(c * HIN + (y0 + r)) * WIN + e];
      }
    }
  };

  auto stage_write = [&](unsigned short dst[CC][LPAD], const float sv[NSG]) {
#pragma unroll
    for (int k = 0; k < NSG; ++k) {
      const int idx = tid + k * TX;
      if (idx < CC * EXT) {
        const int c = idx / EXT;
        const int e = idx - c * EXT;
        dst[c][e] = __builtin_bit_cast(unsigned short, (_Float16)sv[k]);
      }
    }
  };

  auto compute = [&](int r, const unsigned short cur[CC][LPAD]) {
    float vv[KY];
#pragma unroll
    for (int t = 0; t < KY; ++t) {
      const int fy = r - t;
      vv[t] = (fy >= 0 && fy < FF)
                  ? __builtin_nontemporal_load(&verb[(size_t)fy * HW + t * WOUT])
                  : 0.0f;
    }
#pragma unroll
    for (int c = 0; c < CC; ++c) {
      const unsigned short* rp = &cur[c][base4];
      float d[KY] = {};
#pragma unroll
      for (int q = 0; q < NQ; ++q) {
        const uint2 u2 = *reinterpret_cast<const uint2*>(rp + 4 * q);
        const half2v p0 = __builtin_bit_cast(half2v, u2.x);
        const half2v p1 = __builtin_bit_cast(half2v, u2.y);
#pragma unroll
        for (int t = 0; t < KY; ++t) {
          d[t] = fdot2f(p0, hp[t][2 * q], d[t]);
          d[t] = fdot2f(p1, hp[t][2 * q + 1], d[t]);
        }
      }
#pragma unroll
      for (int t = 0; t < KY; ++t) acc[c][t] += d[t] * vv[t];
    }
  };

  // ---- prologue: stage row y0 into buffer 0
  {
    float sv0[NSG];
    stage_load(0, sv0);
    stage_write(sIn[0], sv0);
  }

  // ---- main loop, unrolled x2 with constant buffer indices (provable disjoint)
  for (int r = 0; r < NSTEP; r += 2) {
    float svA[NSG], svB[NSG];
    const bool hasA = (r + 1 < NSTEP);
    const bool hasB = (r + 2 < NSTEP);
    if (hasA) stage_load(r + 1, svA);   // T14: issue loads before compute
    compute(r, sIn[0]);
    if (hasA) {
      stage_write(sIn[1], svA);
      if (hasB) stage_load(r + 2, svB);
      compute(r + 1, sIn[1]);
      if (hasB) stage_write(sIn[0], svB);
    }
  }

  // ---- epilogue: write 3 channels x KY rows
  float* outb = Out + (size_t)b * CC * HW + (size_t)y0 * WOUT + x;
#pragma unroll
  for (int c = 0; c < CC; ++c) {
#pragma unroll
    for (int t = 0; t < KY; ++t) {
      outb[(size_t)c * HW + t * WOUT] = acc[c][t];
    }
  }
}

extern "C" void kernel_launch(void* const* d_in, const int* in_sizes, int n_in,
                              void* d_out, int out_size, void* d_ws, size_t ws_size,
                              hipStream_t stream) {
  const float* In = (const float*)d_in[0];
  const float* Ver = (const float*)d_in[1];
  const float* Hor = (const float*)d_in[2];
  float* Out = (float*)d_out;

  dim3 grid(WOUT / TX, HOUT / KY, 4);
  sepconv_kernel<<<grid, dim3(TX, 1, 1), 0, stream>>>(In, Ver, Hor, Out);
}

// Round 3
// 645.282 us; speedup vs baseline: 1.7281x; 1.7281x over previous
//
#include <hip/hip_runtime.h>

namespace {
constexpr int CC = 3, FF = 51;
constexpr int HOUT = 384, WOUT = 384;
constexpr int HIN = 434, WIN = 434;
constexpr int KY = 4;                 // vertical outputs per thread
constexpr int LANES = 64;             // x-pixels per block
constexpr int NW = 2;                 // fx-split waves per block
constexpr int EXT = LANES + FF - 1;   // 114 valid f16 per channel strip
constexpr int LPAD = 120;             // strip pitch (f16); b64 reads reach elem 119
constexpr int NSTEP = FF + KY - 1;    // 54 input rows per tile
constexpr int NSG = (CC * LPAD + LANES - 1) / LANES;  // 6 staged elems/lane
constexpr int NQW = 8;                // b64 LDS reads per (c, step)
constexpr int NPW = 16;               // f16 pairs per (t, step)
constexpr int SSTRIDE = NW * CC * LPAD;  // u16 elems per LDS buffer (720)

using half2v = _Float16 __attribute__((ext_vector_type(2)));

__device__ __forceinline__ float fdot2f(half2v a, half2v b, float c) {
#if __has_builtin(__builtin_amdgcn_fdot2)
  return __builtin_amdgcn_fdot2(a, b, c, false);
#else
  return c + (float)a.x * (float)b.x + (float)a.y * (float)b.y;
#endif
}
}  // namespace

__global__ __launch_bounds__(NW* LANES, 4) void sepconv_kernel(
    const float* __restrict__ In, const float* __restrict__ Ver,
    const float* __restrict__ Hor, float* __restrict__ Out) {
  const int lane = threadIdx.x;
  const int w = threadIdx.y;          // fx-half
  const int x0 = blockIdx.x * LANES;
  const int y0 = blockIdx.y * KY;
  const int b = blockIdx.z;
  const int x = x0 + lane;
  const int fxBase = 26 * w;          // wave0: taps 0..25, wave1: 26..50
  const int ntaps = (w == 0) ? 26 : 25;
  const int aw = (lane + fxBase) & 3;        // alignment class
  const int bw = lane + fxBase - aw;         // 4-f16-aligned strip base elem

  __shared__ __align__(16) unsigned short sIn[2][NW][CC][LPAD];
  __shared__ float sRed[CC][KY][LANES];
  unsigned short* const sflat = &sIn[0][0][0][0];

  const size_t HW = (size_t)HOUT * WOUT;

  // ---- per-pixel horizontal taps for this wave's fx range (OOB -> 0)
  half2v hp[KY][NPW];
  {
    const float* horx = Hor + (size_t)b * FF * HW + x;
#pragma unroll
    for (int t = 0; t < KY; ++t) {
      const float* hb = horx + (size_t)(y0 + t) * WOUT;
#pragma unroll
      for (int j = 0; j < NPW; ++j) {
        const int u0 = 2 * j - aw;
        const int u1 = u0 + 1;
        float f0 = (u0 >= 0 && u0 < ntaps) ? hb[(size_t)(fxBase + u0) * HW] : 0.0f;
        float f1 = (u1 >= 0 && u1 < ntaps) ? hb[(size_t)(fxBase + u1) * HW] : 0.0f;
        half2v p;
        p.x = (_Float16)f0;  // RTE
        p.y = (_Float16)f1;
        hp[t][j] = p;
      }
    }
  }

  // ---- staging descriptors: idx -> (c, e); soff<0 marks "store 0"
  // inactive lanes of the last chunk dump a 0 into a pad slot (elem LPAD-1).
  const float* inb = In + ((size_t)b * CC * HIN + y0) * WIN + x0;
  int soff[NSG];   // flat In offset (c*HIN*WIN + e), -1 if pad/inactive
  int sbase[NSG];  // u16 index within one LDS buffer
#pragma unroll
  for (int k = 0; k < NSG; ++k) {
    const int idx = lane + k * LANES;
    const bool active = idx < CC * LPAD;
    const int c = idx / LPAD;
    const int e = idx - c * LPAD;
    const bool valid = active && (e < EXT);
    soff[k] = valid ? (c * HIN * WIN + e) : -1;
    sbase[k] = active ? ((w * CC + c) * LPAD + e) : (w * CC * LPAD + LPAD - 1);
  }
  int rbase[CC];
#pragma unroll
  for (int c = 0; c < CC; ++c) rbase[c] = (w * CC + c) * LPAD + bw;

  const float* verb = Ver + (size_t)b * FF * HW + (size_t)y0 * WOUT + x;

  float acc[CC][KY] = {};
  float sv[NSG];

#define STAGE_LOAD(R)                                                        \
  _Pragma("unroll") for (int k = 0; k < NSG; ++k) {                          \
    sv[k] = (soff[k] >= 0) ? inb[(size_t)soff[k] + (size_t)(R) * WIN] : 0.0f;\
  }

#define STAGE_WRITE(BF)                                                      \
  _Pragma("unroll") for (int k = 0; k < NSG; ++k) {                          \
    sflat[(BF)*SSTRIDE + sbase[k]] =                                         \
        __builtin_bit_cast(unsigned short, (_Float16)sv[k]);                 \
  }

#define COMPUTE(R, BF)                                                       \
  {                                                                          \
    float vv[KY];                                                            \
    _Pragma("unroll") for (int t = 0; t < KY; ++t) {                         \
      const int u = (R)-t;                                                   \
      vv[t] = (u >= 0 && u < FF)                                             \
                  ? verb[(size_t)u * HW + (size_t)t * WOUT]                  \
                  : 0.0f;                                                    \
    }                                                                        \
    _Pragma("unroll") for (int c = 0; c < CC; ++c) {                         \
      const unsigned short* rp = sflat + (BF)*SSTRIDE + rbase[c];            \
      float d[KY] = {};                                                      \
      _Pragma("unroll") for (int q = 0; q < NQW; ++q) {                      \
        const uint2 u2 = *reinterpret_cast<const uint2*>(rp + 4 * q);        \
        const half2v p0 = __builtin_bit_cast(half2v, u2.x);                  \
        const half2v p1 = __builtin_bit_cast(half2v, u2.y);                  \
        _Pragma("unroll") for (int t = 0; t < KY; ++t) {                     \
          d[t] = fdot2f(p0, hp[t][2 * q], d[t]);                             \
          d[t] = fdot2f(p1, hp[t][2 * q + 1], d[t]);                         \
        }                                                                    \
      }                                                                      \
      _Pragma("unroll") for (int t = 0; t < KY; ++t) acc[c][t] += d[t] * vv[t];\
    }                                                                        \
  }

  // ---- prologue: stage input row y0 into buffer 0 (wave-private, no barriers)
  STAGE_LOAD(0);
  STAGE_WRITE(0);

  // ---- main loop, 2x unrolled, constant buffer indices, barrier-free
#pragma unroll 1
  for (int r = 0; r < NSTEP; r += 2) {
    STAGE_LOAD(r + 1);  // issue early (T14); consumed after COMPUTE(r)
    COMPUTE(r, 0);
    STAGE_WRITE(1);
    const bool more = (r + 2 < NSTEP);
    if (more) { STAGE_LOAD(r + 2); }
    COMPUTE(r + 1, 1);
    if (more) { STAGE_WRITE(0); }
  }

  // ---- cross-wave fx reduction, then store
  if (w == 1) {
#pragma unroll
    for (int c = 0; c < CC; ++c)
#pragma unroll
      for (int t = 0; t < KY; ++t) sRed[c][t][lane] = acc[c][t];
  }
  __syncthreads();
  if (w == 0) {
    float* outb = Out + (size_t)b * CC * HW + (size_t)y0 * WOUT + x0 + lane;
#pragma unroll
    for (int c = 0; c < CC; ++c)
#pragma unroll
      for (int t = 0; t < KY; ++t)
        outb[(size_t)c * HW + (size_t)t * WOUT] = acc[c][t] + sRed[c][t][lane];
  }
#undef STAGE_LOAD
#undef STAGE_WRITE
#undef COMPUTE
}

extern "C" void kernel_launch(void* const* d_in, const int* in_sizes, int n_in,
                              void* d_out, int out_size, void* d_ws, size_t ws_size,
                              hipStream_t stream) {
  const float* In = (const float*)d_in[0];
  const float* Ver = (const float*)d_in[1];
  const float* Hor = (const float*)d_in[2];
  float* Out = (float*)d_out;

  dim3 grid(WOUT / LANES, HOUT / KY, 4);
  dim3 block(LANES, NW, 1);
  sepconv_kernel<<<grid, block, 0, stream>>>(In, Ver, Hor, Out);
}

// Round 4
// 166.608 us; speedup vs baseline: 6.6930x; 3.8730x over previous
//
#include <hip/hip_runtime.h>

namespace {
constexpr int CC = 3, FF = 51;
constexpr int HOUT = 384, WOUT = 384;
constexpr int HIN = 434, WIN = 434;
constexpr int KY = 4;                 // vertical outputs per thread
constexpr int LANES = 64;             // x-pixels per block
constexpr int NW = 2;                 // fx-split waves per block
constexpr int EXT = LANES + FF - 1;   // 114 valid f16 per channel strip
constexpr int LPAD = 128;             // strip pitch (f16), pow2 -> static indices
constexpr int NSTEP = FF + KY - 1;    // 54 input rows per tile
constexpr int NSG = CC * LPAD / LANES;   // 6 staged elems/lane (exact)
constexpr int NQW = 8;                // b64 LDS reads per (c, step)
constexpr int NPW = 16;               // f16 pairs per (t, step)
constexpr int SSTRIDE = NW * CC * LPAD;  // u16 elems per LDS buffer (768)

using half2v = _Float16 __attribute__((ext_vector_type(2)));

__device__ __forceinline__ float fdot2f(half2v a, half2v b, float c) {
#if __has_builtin(__builtin_amdgcn_fdot2)
  return __builtin_amdgcn_fdot2(a, b, c, false);
#else
  return c + (float)a.x * (float)b.x + (float)a.y * (float)b.y;
#endif
}
}  // namespace

__global__ __launch_bounds__(NW* LANES, 2) void sepconv_kernel(
    const float* __restrict__ In, const float* __restrict__ Ver,
    const float* __restrict__ Hor, float* __restrict__ Out) {
  const int lane = threadIdx.x;
  const int w = threadIdx.y;          // fx-half
  const int x0 = blockIdx.x * LANES;
  const int y0 = blockIdx.y * KY;
  const int b = blockIdx.z;
  const int x = x0 + lane;
  const int fxBase = 26 * w;          // wave0: taps 0..25, wave1: 26..50
  const int ntaps = (w == 0) ? 26 : 25;
  const int aw = (lane + fxBase) & 3;        // alignment class
  const int bw = lane + fxBase - aw;         // 4-f16-aligned strip base elem

  __shared__ __align__(16) unsigned short sIn[2][NW][CC][LPAD];
  __shared__ float sRed[CC][KY][LANES];
  unsigned short* const sflat = &sIn[0][0][0][0];

  const size_t HW = (size_t)HOUT * WOUT;

  // ---- per-pixel horizontal taps for this wave's fx range (OOB -> 0)
  half2v hp[KY][NPW];
  {
    const float* horx = Hor + (size_t)b * FF * HW + x;
#pragma unroll
    for (int t = 0; t < KY; ++t) {
      const float* hb = horx + (size_t)(y0 + t) * WOUT;
#pragma unroll
      for (int j = 0; j < NPW; ++j) {
        const int u0 = 2 * j - aw;
        const int u1 = u0 + 1;
        float f0 = (u0 >= 0 && u0 < ntaps) ? hb[(size_t)(fxBase + u0) * HW] : 0.0f;
        float f1 = (u1 >= 0 && u1 < ntaps) ? hb[(size_t)(fxBase + u1) * HW] : 0.0f;
        half2v p;
        p.x = (_Float16)f0;  // RTE
        p.y = (_Float16)f1;
        hp[t][j] = p;
      }
    }
  }

  const float* inb = In + ((size_t)b * CC * HIN + y0) * WIN + x0;
  const float* verb = Ver + (size_t)b * FF * HW + (size_t)y0 * WOUT + x;

  // LDS read bases per channel (4-f16 aligned -> b64 reads)
  int rbase[CC];
#pragma unroll
  for (int c = 0; c < CC; ++c) rbase[c] = (w * CC + c) * LPAD + bw;

  float acc[CC][KY] = {};
  float sv[NSG];

  // Staging geometry (all indices compile-time per k):
  //   k: c = k>>1, e = lane + (k&1)*64.  e >= EXT (i.e. odd k, lane >= 50)
  //   stores 0.0 into the pad region so b64 over-reads see zeros.
  //   x0 + EXT - 1 = 433 < WIN -> no x guard needed.
#define STAGE_LOAD(R)                                                         \
  _Pragma("unroll") for (int k = 0; k < NSG; ++k) {                           \
    const int e = lane + (k & 1) * 64;                                        \
    const bool valid = ((k & 1) == 0) || (lane < EXT - LANES);                \
    sv[k] = valid ? inb[(size_t)((k >> 1) * HIN + (R)) * WIN + e] : 0.0f;     \
  }

#define STAGE_WRITE(BF)                                                       \
  _Pragma("unroll") for (int k = 0; k < NSG; ++k) {                           \
    const int e = lane + (k & 1) * 64;                                        \
    sflat[(BF)*SSTRIDE + (w * CC + (k >> 1)) * LPAD + e] =                    \
        __builtin_bit_cast(unsigned short, (_Float16)sv[k]);                  \
  }

#define COMPUTE(R, BF)                                                        \
  {                                                                           \
    float vv[KY];                                                             \
    _Pragma("unroll") for (int t = 0; t < KY; ++t) {                          \
      const int u = (R)-t;                                                    \
      vv[t] = (u >= 0 && u < FF)                                              \
                  ? verb[(size_t)u * HW + (size_t)t * WOUT]                   \
                  : 0.0f;                                                     \
    }                                                                         \
    _Pragma("unroll") for (int c = 0; c < CC; ++c) {                          \
      const unsigned short* rp = sflat + (BF)*SSTRIDE + rbase[c];             \
      float d[KY] = {};                                                       \
      _Pragma("unroll") for (int q = 0; q < NQW; ++q) {                       \
        const uint2 u2 = *reinterpret_cast<const uint2*>(rp + 4 * q);         \
        const half2v p0 = __builtin_bit_cast(half2v, u2.x);                   \
        const half2v p1 = __builtin_bit_cast(half2v, u2.y);                   \
        _Pragma("unroll") for (int t = 0; t < KY; ++t) {                      \
          d[t] = fdot2f(p0, hp[t][2 * q], d[t]);                              \
          d[t] = fdot2f(p1, hp[t][2 * q + 1], d[t]);                          \
        }                                                                     \
      }                                                                       \
      _Pragma("unroll") for (int t = 0; t < KY; ++t) acc[c][t] += d[t] * vv[t];\
    }                                                                         \
  }

  // ---- prologue: stage input row y0 into buffer 0 (wave-private, no barriers)
  STAGE_LOAD(0);
  STAGE_WRITE(0);

  // ---- main loop, 2x unrolled, constant buffer indices, barrier-free
#pragma unroll 1
  for (int r = 0; r < NSTEP; r += 2) {
    STAGE_LOAD(r + 1);  // issue early (T14); consumed after COMPUTE(r)
    COMPUTE(r, 0);
    STAGE_WRITE(1);
    const bool more = (r + 2 < NSTEP);
    if (more) { STAGE_LOAD(r + 2); }
    COMPUTE(r + 1, 1);
    if (more) { STAGE_WRITE(0); }
  }

  // ---- cross-wave fx reduction, then store
  if (w == 1) {
#pragma unroll
    for (int c = 0; c < CC; ++c)
#pragma unroll
      for (int t = 0; t < KY; ++t) sRed[c][t][lane] = acc[c][t];
  }
  __syncthreads();
  if (w == 0) {
    float* outb = Out + (size_t)b * CC * HW + (size_t)y0 * WOUT + x0 + lane;
#pragma unroll
    for (int c = 0; c < CC; ++c)
#pragma unroll
      for (int t = 0; t < KY; ++t)
        outb[(size_t)c * HW + (size_t)t * WOUT] = acc[c][t] + sRed[c][t][lane];
  }
#undef STAGE_LOAD
#undef STAGE_WRITE
#undef COMPUTE
}

extern "C" void kernel_launch(void* const* d_in, const int* in_sizes, int n_in,
                              void* d_out, int out_size, void* d_ws, size_t ws_size,
                              hipStream_t stream) {
  const float* In = (const float*)d_in[0];
  const float* Ver = (const float*)d_in[1];
  const float* Hor = (const float*)d_in[2];
  float* Out = (float*)d_out;

  dim3 grid(WOUT / LANES, HOUT / KY, 4);
  dim3 block(LANES, NW, 1);
  sepconv_kernel<<<grid, block, 0, stream>>>(In, Ver, Hor, Out);
}

// Round 6
// 163.886 us; speedup vs baseline: 6.8041x; 1.0166x over previous
//
#include <hip/hip_runtime.h>

namespace {
constexpr int CC = 3, FF = 51;
constexpr int HOUT = 384, WOUT = 384;
constexpr int HIN = 434, WIN = 434;
constexpr int KY = 4;                 // vertical outputs per thread
constexpr int LANES = 64;             // x-pixels per block
constexpr int NW = 4;                 // fx-split waves per block (13/13/13/12 taps)
constexpr int EXT = LANES + FF - 1;   // 114 valid f16 per channel strip
constexpr int LPAD = 128;             // strip pitch (f16), pow2 -> static indices
constexpr int NSTEP = FF + KY - 1;    // 54 input rows per tile
constexpr int NSG = CC * LPAD / LANES;   // 6 staged elems/lane (exact)
constexpr int NQW = 4;                // b64 LDS reads per (c, step)
constexpr int NPW = 8;                // f16 pairs per (t, step)
constexpr int SSTRIDE = NW * CC * LPAD;  // u16 elems per LDS buffer (1536)

using half2v = _Float16 __attribute__((ext_vector_type(2)));

// r4-proven path: __builtin_amdgcn_fdot2 emits v_dot2_f32_f16 (timing analysis
// of r4 shows the real instruction was used; raw inline asm in r5 broke
// numerics — do NOT hand-write VOP3P here).
__device__ __forceinline__ float fdot2f(half2v a, half2v b, float c) {
#if __has_builtin(__builtin_amdgcn_fdot2)
  return __builtin_amdgcn_fdot2(a, b, c, false);
#else
  return c + (float)a.x * (float)b.x + (float)a.y * (float)b.y;
#endif
}
}  // namespace

__global__ __launch_bounds__(NW* LANES, 2) void sepconv_kernel(
    const float* __restrict__ In, const float* __restrict__ Ver,
    const float* __restrict__ Hor, float* __restrict__ Out) {
  const int lane = threadIdx.x;
  const int w = threadIdx.y;          // fx-quarter
  const int x0 = blockIdx.x * LANES;
  const int y0 = blockIdx.y * KY;
  const int b = blockIdx.z;
  const int x = x0 + lane;
  const int fxBase = 13 * w;          // taps [fxBase, fxBase+ntaps)
  const int ntaps = (w < 3) ? 13 : 12;
  const int aw = (lane + fxBase) & 3;        // alignment class
  const int bw = lane + fxBase - aw;         // 4-f16-aligned strip base elem

  __shared__ __align__(16) unsigned short sIn[2][NW][CC][LPAD];
  __shared__ float sRed[NW - 1][CC][KY][LANES];
  unsigned short* const sflat = &sIn[0][0][0][0];

  const size_t HW = (size_t)HOUT * WOUT;

  // ---- per-pixel horizontal taps for this wave's fx range (OOB -> 0)
  half2v hp[KY][NPW];
  {
    const float* horx = Hor + (size_t)b * FF * HW + x;
#pragma unroll
    for (int t = 0; t < KY; ++t) {
      const float* hb = horx + (size_t)(y0 + t) * WOUT;
#pragma unroll
      for (int j = 0; j < NPW; ++j) {
        const int u0 = 2 * j - aw;
        const int u1 = u0 + 1;
        float f0 = (u0 >= 0 && u0 < ntaps) ? hb[(size_t)(fxBase + u0) * HW] : 0.0f;
        float f1 = (u1 >= 0 && u1 < ntaps) ? hb[(size_t)(fxBase + u1) * HW] : 0.0f;
        half2v p;
        p.x = (_Float16)f0;  // RTE
        p.y = (_Float16)f1;
        hp[t][j] = p;
      }
    }
  }

  const float* inb = In + ((size_t)b * CC * HIN + y0) * WIN + x0;
  const float* verb = Ver + (size_t)b * FF * HW + (size_t)y0 * WOUT + x;

  float acc[CC][KY] = {};
  float sv[NSG];

  // Staging geometry (indices compile-time per k):
  //   k: c = k>>1, e = lane + (k&1)*64. Odd-k lanes with e >= EXT store 0.0
  //   into the pad region so b64 over-reads (up to elem 115) see zeros.
  //   x0 + EXT - 1 = 433 < WIN=434 -> no x guard needed.
#define STAGE_LOAD(R)                                                         \
  _Pragma("unroll") for (int k = 0; k < NSG; ++k) {                           \
    const int e = lane + (k & 1) * 64;                                        \
    const bool valid = ((k & 1) == 0) || (lane < EXT - LANES);                \
    sv[k] = valid ? inb[(size_t)((k >> 1) * HIN + (R)) * WIN + e] : 0.0f;     \
  }

#define STAGE_WRITE(BF)                                                       \
  _Pragma("unroll") for (int k = 0; k < NSG; ++k) {                           \
    const int e = lane + (k & 1) * 64;                                        \
    sflat[(BF)*SSTRIDE + (w * CC + (k >> 1)) * LPAD + e] =                    \
        __builtin_bit_cast(unsigned short, (_Float16)sv[k]);                  \
  }

#define COMPUTE(R, BF)                                                        \
  {                                                                           \
    float vv[KY];                                                             \
    _Pragma("unroll") for (int t = 0; t < KY; ++t) {                          \
      const int u = (R)-t;                                                    \
      vv[t] = (u >= 0 && u < FF)                                              \
                  ? verb[(size_t)u * HW + (size_t)t * WOUT]                   \
                  : 0.0f;                                                     \
    }                                                                         \
    _Pragma("unroll") for (int c = 0; c < CC; ++c) {                          \
      const unsigned short* rp = sflat + (BF)*SSTRIDE + (w * CC + c) * LPAD + bw; \
      float d[KY] = {};                                                       \
      _Pragma("unroll") for (int q = 0; q < NQW; ++q) {                       \
        const uint2 u2 = *reinterpret_cast<const uint2*>(rp + 4 * q);         \
        const half2v p0 = __builtin_bit_cast(half2v, u2.x);                   \
        const half2v p1 = __builtin_bit_cast(half2v, u2.y);                   \
        _Pragma("unroll") for (int t = 0; t < KY; ++t) {                      \
          d[t] = fdot2f(p0, hp[t][2 * q], d[t]);                              \
          d[t] = fdot2f(p1, hp[t][2 * q + 1], d[t]);                          \
        }                                                                     \
      }                                                                       \
      _Pragma("unroll") for (int t = 0; t < KY; ++t) acc[c][t] += d[t] * vv[t];\
    }                                                                         \
  }

  // ---- prologue: stage input row y0 into buffer 0 (wave-private, no barriers)
  STAGE_LOAD(0);
  STAGE_WRITE(0);

  // ---- main loop, 2x unrolled, constant buffer indices, barrier-free
#pragma unroll 1
  for (int r = 0; r < NSTEP; r += 2) {
    STAGE_LOAD(r + 1);  // issue early (T14); consumed after COMPUTE(r)
    COMPUTE(r, 0);
    STAGE_WRITE(1);
    const bool more = (r + 2 < NSTEP);
    if (more) { STAGE_LOAD(r + 2); }
    COMPUTE(r + 1, 1);
    if (more) { STAGE_WRITE(0); }
  }

  // ---- cross-wave fx reduction (4-way), then store
  if (w > 0) {
#pragma unroll
    for (int c = 0; c < CC; ++c)
#pragma unroll
      for (int t = 0; t < KY; ++t) sRed[w - 1][c][t][lane] = acc[c][t];
  }
  __syncthreads();
  if (w == 0) {
    float* outb = Out + (size_t)b * CC * HW + (size_t)y0 * WOUT + x0 + lane;
#pragma unroll
    for (int c = 0; c < CC; ++c)
#pragma unroll
      for (int t = 0; t < KY; ++t)
        outb[(size_t)c * HW + (size_t)t * WOUT] =
            acc[c][t] + sRed[0][c][t][lane] + sRed[1][c][t][lane] +
            sRed[2][c][t][lane];
  }
#undef STAGE_LOAD
#undef STAGE_WRITE
#undef COMPUTE
}

extern "C" void kernel_launch(void* const* d_in, const int* in_sizes, int n_in,
                              void* d_out, int out_size, void* d_ws, size_t ws_size,
                              hipStream_t stream) {
  const float* In = (const float*)d_in[0];
  const float* Ver = (const float*)d_in[1];
  const float* Hor = (const float*)d_in[2];
  float* Out = (float*)d_out;

  dim3 grid(WOUT / LANES, HOUT / KY, 4);
  dim3 block(LANES, NW, 1);
  sepconv_kernel<<<grid, block, 0, stream>>>(In, Ver, Hor, Out);
}